// Round 19
// baseline (176.047 us; speedup 1.0000x reference)
//
#include <hip/hip_runtime.h>
#include <hip/hip_bf16.h>
#include <cstddef>

#define NN 100000
#define NE 1600000
#define INF 256
#define OUTF 128
#define NBKT 196      // buckets: node>>9
#define BSH 9
#define P1B 250       // pass-1 blocks
#define EPB 6400      // edges per pass-1 block (NE/P1B)
#define SCL (NBKT * P1B)  // 49000
#define SCLP 49152    // padded to 1024*48
#define P2CAP 10240   // p2 LDS sort capacity
#define NGB 782       // gemm blocks = ceil(NN/128)

typedef __bf16 bf16x8 __attribute__((ext_vector_type(8)));
typedef float f32x4 __attribute__((ext_vector_type(4)));

__device__ __forceinline__ float bflo(uint v) { return __uint_as_float(v << 16); }
__device__ __forceinline__ float bfhi(uint v) { return __uint_as_float(v & 0xffff0000u); }

// ---------------- K1: fused [gemm blocks | p1a histogram blocks] ----------------
// gemm: h = feat @ W (row-major bf16, NO ns fold). B self-staged from fp32 W
// (coalesced read + in-LDS transpose/swizzle). A direct global->reg depth-4 ring.
// p1a: per-block bucket histograms of dst/src (runs concurrently with gemm).
__global__ __launch_bounds__(512, 4) void k1(const float* __restrict__ feat,
                                             const float* __restrict__ Wm,
                                             __bf16* __restrict__ h,
                                             const int* __restrict__ src,
                                             const int* __restrict__ dst,
                                             int* __restrict__ ghd,
                                             int* __restrict__ ghs) {
  __shared__ __attribute__((aligned(16))) char lmem[65536];
  const int tid = threadIdx.x;

  if (blockIdx.x >= NGB) {
    // ---------- p1a histogram block ----------
    const int b = blockIdx.x - NGB;
    int* lhd = (int*)lmem;
    int* lhs = ((int*)lmem) + 256;
    if (b == 0 && tid < SCLP - SCL) { ghd[SCL + tid] = 0; ghs[SCL + tid] = 0; }
    if (tid < NBKT) { lhd[tid] = 0; lhs[tid] = 0; }
    __syncthreads();
    const int base = b * EPB;
    for (int e = base + tid; e < base + EPB; e += 512) {
      atomicAdd(&lhd[dst[e] >> BSH], 1);
      atomicAdd(&lhs[src[e] >> BSH], 1);
    }
    __syncthreads();
    if (tid < NBKT) {
      ghd[tid * P1B + b] = lhd[tid];
      ghs[tid * P1B + b] = lhs[tid];
    }
    return;
  }

  // ---------- gemm block ----------
  char* lB = lmem;
  const int w = tid >> 6, l = tid & 63;
  const int lr = l & 15, kg = l >> 4;
  const int row0 = blockIdx.x * 128 + w * 16;

  // stage W (fp32 [256][128]) -> lB bf16 [col][k-granule] swizzled.
  // chunk c = 8 consecutive fp32 of one W row: k = c>>4, n0 = (c&15)*8.
  {
    const float4* W4 = (const float4*)Wm;
#pragma unroll
    for (int i = 0; i < 8; ++i) {
      int c = i * 512 + tid;
      int k = c >> 4, n0 = (c & 15) << 3;
      float4 f0 = W4[c * 2], f1 = W4[c * 2 + 1];
      int g = k >> 3, kb = (k & 7) * 2;
      float ff[8] = {f0.x, f0.y, f0.z, f0.w, f1.x, f1.y, f1.z, f1.w};
#pragma unroll
      for (int j = 0; j < 8; ++j)
        *(__bf16*)(lB + (n0 + j) * 512 + ((g ^ j) * 16) + kb) = (__bf16)ff[j];
    }
  }
  __syncthreads();

  int r0 = row0 + lr; if (r0 >= NN) r0 = NN - 1;
  const float4* ap4k = (const float4*)(feat + (size_t)r0 * INF) + kg * 2;

  f32x4 acc[8];
#pragma unroll
  for (int j = 0; j < 8; ++j) acc[j] = (f32x4)0.0f;

  const char* bb = lB + lr * 512;
  const int lx = lr & 7;

  float4 buf0[4], buf1[4];
#pragma unroll
  for (int i = 0; i < 4; ++i) {
    buf0[i] = ap4k[i * 8];
    buf1[i] = ap4k[i * 8 + 1];
  }
#pragma unroll
  for (int kk = 0; kk < 8; ++kk) {
    float4 c0 = buf0[kk & 3], c1 = buf1[kk & 3];
    if (kk < 4) {
      buf0[kk & 3] = ap4k[(kk + 4) * 8];
      buf1[kk & 3] = ap4k[(kk + 4) * 8 + 1];
    }
    bf16x8 a;
#pragma unroll
    for (int j = 0; j < 4; ++j) {
      a[j] = (__bf16)c0[j];
      a[4 + j] = (__bf16)c1[j];
    }
#pragma unroll
    for (int nf = 0; nf < 8; ++nf) {
      bf16x8 b = *(const bf16x8*)(bb + nf * 8192 + (((kk * 4 + kg) ^ lx) * 16));
      acc[nf] = __builtin_amdgcn_mfma_f32_16x16x32_bf16(a, b, acc[nf], 0, 0, 0);
    }
  }

#pragma unroll
  for (int r = 0; r < 4; ++r) {
    int row = row0 + kg * 4 + r;
    if (row < NN) {
      __bf16* hp = h + (size_t)row * OUTF + lr;
#pragma unroll
      for (int nf = 0; nf < 8; ++nf)
        hp[nf * 16] = (__bf16)(acc[nf][r]);
    }
  }
}

// ---------------- P1b: exclusive scan, vectorized (int4 x12 per thread, shuffle scan) ----------------
__global__ __launch_bounds__(1024) void k_p1b(int* __restrict__ ghd,
                                              int* __restrict__ ghs,
                                              int* __restrict__ row_start) {
  int* a = blockIdx.x ? ghs : ghd;
  __shared__ int wsum[16];
  const int t = threadIdx.x;
  const int lane = t & 63, wid = t >> 6;
  int4 v[12];
  const int4* p = (const int4*)(a + t * 48);
#pragma unroll
  for (int i = 0; i < 12; ++i) v[i] = p[i];
  int s = 0;
#pragma unroll
  for (int i = 0; i < 12; ++i) s += v[i].x + v[i].y + v[i].z + v[i].w;
  const int mysum = s;
#pragma unroll
  for (int d = 1; d < 64; d <<= 1) {
    int u = __shfl_up(s, d);
    if (lane >= d) s += u;
  }
  if (lane == 63) wsum[wid] = s;
  __syncthreads();
  if (wid == 0) {
    int ws = (lane < 16) ? wsum[lane] : 0;
    int inc = ws;
#pragma unroll
    for (int d = 1; d < 16; d <<= 1) {
      int u = __shfl_up(inc, d);
      if (lane >= d) inc += u;
    }
    if (lane < 16) wsum[lane] = inc - ws;  // exclusive wave offset
  }
  __syncthreads();
  int ex = wsum[wid] + s - mysum;
#pragma unroll
  for (int i = 0; i < 12; ++i) {
    int4 w;
    w.x = ex; ex += v[i].x;
    w.y = ex; ex += v[i].y;
    w.z = ex; ex += v[i].z;
    w.w = ex; ex += v[i].w;
    ((int4*)(a + t * 48))[i] = w;
  }
  if (blockIdx.x == 0 && t == 0) row_start[NN] = NE;
}

// ---------------- P1c: LDS staging-sort then coalesced flush (rec_d, rec_s) ----------------
__global__ __launch_bounds__(256) void k_p1c(const int* __restrict__ src,
                                             const int* __restrict__ dst,
                                             const int* __restrict__ ghd,
                                             const int* __restrict__ ghs,
                                             uint* __restrict__ rec_d,
                                             ushort* __restrict__ rec_s) {
  __shared__ int hist[256];
  __shared__ int off[NBKT];
  __shared__ int adj[NBKT];
  __shared__ int sc[256];
  __shared__ uint d4[EPB];
  __shared__ unsigned char bkt[EPB];
  const int t = threadIdx.x;
  const int base = blockIdx.x * EPB;

  // ========== Phase D ==========
  hist[t] = 0;
  __syncthreads();
#pragma unroll
  for (int i = 0; i < EPB / 256; ++i)
    atomicAdd(&hist[dst[base + i * 256 + t] >> BSH], 1);
  __syncthreads();
  int hv = hist[t];
  sc[t] = hv;
  __syncthreads();
  for (int o = 1; o < 256; o <<= 1) {
    int add = (t >= o) ? sc[t - o] : 0;
    __syncthreads();
    sc[t] += add;
    __syncthreads();
  }
  int lstart = sc[t] - hv;
  if (t < NBKT) {
    off[t] = lstart;
    adj[t] = ghd[t * P1B + blockIdx.x] - lstart;
  }
  __syncthreads();
#pragma unroll
  for (int i = 0; i < EPB / 256; ++i) {
    int e = base + i * 256 + t;
    int s = src[e], d = dst[e];
    int b = d >> BSH;
    int p = atomicAdd(&off[b], 1);
    d4[p] = ((uint)s << BSH) | (uint)(d & 511);
    bkt[p] = (unsigned char)b;
  }
  __syncthreads();
#pragma unroll
  for (int i = 0; i < EPB / 256; ++i) {
    int idx = i * 256 + t;
    rec_d[adj[bkt[idx]] + idx] = d4[idx];
  }
  __syncthreads();

  // ========== Phase S ==========
  hist[t] = 0;
  __syncthreads();
#pragma unroll
  for (int i = 0; i < EPB / 256; ++i)
    atomicAdd(&hist[src[base + i * 256 + t] >> BSH], 1);
  __syncthreads();
  hv = hist[t];
  sc[t] = hv;
  __syncthreads();
  for (int o = 1; o < 256; o <<= 1) {
    int add = (t >= o) ? sc[t - o] : 0;
    __syncthreads();
    sc[t] += add;
    __syncthreads();
  }
  lstart = sc[t] - hv;
  if (t < NBKT) {
    off[t] = lstart;
    adj[t] = ghs[t * P1B + blockIdx.x] - lstart;
  }
  __syncthreads();
  ushort* s2 = (ushort*)d4;
#pragma unroll
  for (int i = 0; i < EPB / 256; ++i) {
    int s = src[base + i * 256 + t];
    int b = s >> BSH;
    int p = atomicAdd(&off[b], 1);
    s2[p] = (ushort)(s & 511);
    bkt[p] = (unsigned char)b;
  }
  __syncthreads();
#pragma unroll
  for (int i = 0; i < EPB / 256; ++i) {
    int idx = i * 256 + t;
    rec_s[adj[bkt[idx]] + idx] = s2[idx];
  }
}

// ---------------- P2: per-bucket CSR build (LDS sort + coalesced flush) + ns ----------------
__global__ __launch_bounds__(256) void k_p2(const int* __restrict__ ghd,
                                            const int* __restrict__ ghs,
                                            const uint* __restrict__ rec_d,
                                            const ushort* __restrict__ rec_s,
                                            int* __restrict__ edge_src,
                                            int* __restrict__ row_start,
                                            float* __restrict__ ns) {
  __shared__ int lh[512];
  __shared__ int sc[256];
  __shared__ int lbuf[P2CAP];
  const int k = blockIdx.x, t = threadIdx.x;
  {
    const int base = ghd[k * P1B];
    const int end = (k == NBKT - 1) ? NE : ghd[(k + 1) * P1B];
    const int cnt = end - base;
    lh[t] = 0; lh[t + 256] = 0;
    __syncthreads();
    for (int j = base + t; j < end; j += 256) atomicAdd(&lh[rec_d[j] & 511], 1);
    __syncthreads();
    int a0 = lh[2 * t], a1 = lh[2 * t + 1];
    sc[t] = a0 + a1;
    __syncthreads();
    for (int off = 1; off < 256; off <<= 1) {
      int add = (t >= off) ? sc[t - off] : 0;
      __syncthreads();
      sc[t] += add;
      __syncthreads();
    }
    int ex = t ? sc[t - 1] : 0;
    int e0 = ex, e1 = ex + a0;
    int n0 = k * 512 + 2 * t;
    if (n0 < NN) row_start[n0] = base + e0;
    if (n0 + 1 < NN) row_start[n0 + 1] = base + e1;
    __syncthreads();
    lh[2 * t] = e0;
    lh[2 * t + 1] = e1;
    __syncthreads();
    if (cnt <= P2CAP) {
      for (int j = base + t; j < end; j += 256) {
        uint r = rec_d[j];
        int p = atomicAdd(&lh[r & 511], 1);
        lbuf[p] = (int)(r >> BSH);
      }
      __syncthreads();
      for (int i = t; i < cnt; i += 256)
        edge_src[base + i] = lbuf[i];
    } else {
      for (int j = base + t; j < end; j += 256) {
        uint r = rec_d[j];
        int p = atomicAdd(&lh[r & 511], 1);
        edge_src[base + p] = (int)(r >> BSH);
      }
    }
  }
  __syncthreads();
  {
    const int base = ghs[k * P1B];
    const int end = (k == NBKT - 1) ? NE : ghs[(k + 1) * P1B];
    lh[t] = 0; lh[t + 256] = 0;
    __syncthreads();
    for (int j = base + t; j < end; j += 256) atomicAdd(&lh[rec_s[j]], 1);
    __syncthreads();
    int n0 = k * 512 + t, n1 = n0 + 256;
    if (n0 < NN) { int c = lh[t];       ns[n0] = rsqrtf((float)(c > 1 ? c : 1)); }
    if (n1 < NN) { int c = lh[t + 256]; ns[n1] = rsqrtf((float)(c > 1 ? c : 1)); }
  }
}

// ---------------- aggregation: out[n] = nd[n] * (sum ns[s] * h[s]) + b ----------------
// r15 structure + per-edge ns gather (ns table 400KB = L2-resident).
__global__ __launch_bounds__(256) void k_aggr(const uint4* __restrict__ h4,
                                              const int* __restrict__ row_start,
                                              const float* __restrict__ ns,
                                              const int* __restrict__ edge_src,
                                              const float* __restrict__ bias,
                                              float* __restrict__ out) {
  const int wave = threadIdx.x >> 6;
  const int lane = threadIdx.x & 63;
  const int q = lane >> 4;    // quarter 0..3
  const int cl = lane & 15;   // 16B chunk within 256B row
  const int n = blockIdx.x * 4 + wave;  // grid = NN/4 exact
  const int s0 = row_start[n];
  const int s1 = row_start[n + 1];
  const int cnt = s1 - s0;

  float a0 = 0.f, a1 = 0.f, a2 = 0.f, a3 = 0.f, a4 = 0.f, a5 = 0.f, a6 = 0.f, a7 = 0.f;
  for (int j0 = 0; j0 < cnt; j0 += 64) {
    int nb = cnt - j0; if (nb > 64) nb = 64;
    int idv = 0; float nsv = 0.f;
    if (lane < nb) { idv = edge_src[s0 + j0 + lane]; nsv = ns[idv]; }
#pragma unroll 8
    for (int j = 0; j < nb; j += 4) {
      int jj = j + q;
      int e = __shfl(idv, jj);
      float w2 = __shfl(nsv, jj);
      if (jj < nb) {
        uint4 v = h4[(size_t)e * 16 + cl];
        a0 += w2 * bflo(v.x); a1 += w2 * bfhi(v.x);
        a2 += w2 * bflo(v.y); a3 += w2 * bfhi(v.y);
        a4 += w2 * bflo(v.z); a5 += w2 * bfhi(v.z);
        a6 += w2 * bflo(v.w); a7 += w2 * bfhi(v.w);
      }
    }
  }
  a0 += __shfl_xor(a0, 16); a1 += __shfl_xor(a1, 16); a2 += __shfl_xor(a2, 16); a3 += __shfl_xor(a3, 16);
  a4 += __shfl_xor(a4, 16); a5 += __shfl_xor(a5, 16); a6 += __shfl_xor(a6, 16); a7 += __shfl_xor(a7, 16);
  a0 += __shfl_xor(a0, 32); a1 += __shfl_xor(a1, 32); a2 += __shfl_xor(a2, 32); a3 += __shfl_xor(a3, 32);
  a4 += __shfl_xor(a4, 32); a5 += __shfl_xor(a5, 32); a6 += __shfl_xor(a6, 32); a7 += __shfl_xor(a7, 32);

  if (q == 0) {
    float ndv = rsqrtf((float)(cnt > 1 ? cnt : 1));
    const float4* b4 = (const float4*)bias;
    float4 ba = b4[2 * cl], bb = b4[2 * cl + 1];
    float4 o0, o1;
    o0.x = a0 * ndv + ba.x; o0.y = a1 * ndv + ba.y; o0.z = a2 * ndv + ba.z; o0.w = a3 * ndv + ba.w;
    o1.x = a4 * ndv + bb.x; o1.y = a5 * ndv + bb.y; o1.z = a6 * ndv + bb.z; o1.w = a7 * ndv + bb.w;
    float4* op = (float4*)(out + (size_t)n * OUTF);
    op[2 * cl] = o0;
    op[2 * cl + 1] = o1;
  }
}

// ---------------- launch ----------------
extern "C" void kernel_launch(void* const* d_in, const int* in_sizes, int n_in,
                              void* d_out, int out_size, void* d_ws, size_t ws_size,
                              hipStream_t stream) {
  const float* feat = (const float*)d_in[0];
  const int* src = (const int*)d_in[1];
  const int* dst = (const int*)d_in[2];
  const float* Wm = (const float*)d_in[3];
  const float* bias = (const float*)d_in[4];
  float* out = (float*)d_out;

  char* ws = (char*)d_ws;
  __bf16* h        = (__bf16*)(ws + 0);            // 25,600,000 (row-major)
  int*    ghd      = (int*)(ws + 25665536);        //    196,608 (padded)
  int*    ghs      = (int*)(ws + 25862144);        //    196,608 (padded)
  uint*   rec_d    = (uint*)(ws + 26058752);       //  6,400,000
  ushort* rec_s    = (ushort*)(ws + 32458752);     //  3,200,000
  int*    edge_src = (int*)(ws + 35658752);        //  6,400,000
  int*    row_start= (int*)(ws + 42058752);        //    400,016
  float*  ns       = (float*)(ws + 42458768);      //    400,000

  k1<<<NGB + P1B, 512, 0, stream>>>(feat, Wm, h, src, dst, ghd, ghs);
  k_p1b<<<2, 1024, 0, stream>>>(ghd, ghs, row_start);
  k_p1c<<<P1B, 256, 0, stream>>>(src, dst, ghd, ghs, rec_d, rec_s);
  k_p2<<<NBKT, 256, 0, stream>>>(ghd, ghs, rec_d, rec_s, edge_src, row_start, ns);
  k_aggr<<<NN / 4, 256, 0, stream>>>((const uint4*)h, row_start, ns, edge_src, bias, out);
}

// Round 20
// 164.553 us; speedup vs baseline: 1.0698x; 1.0698x over previous
//
#include <hip/hip_runtime.h>
#include <hip/hip_bf16.h>
#include <cstddef>

#define NN 100000
#define NE 1600000
#define INF 256
#define OUTF 128
#define NBKT 196      // buckets: node>>9
#define BSH 9
#define P1B 250       // pass-1 blocks
#define EPB 6400      // edges per pass-1 block (NE/P1B)
#define SCL (NBKT * P1B)  // 49000
#define SCLP 49152    // padded to 1024*48
#define P2CAP 10240   // p2 LDS sort capacity (bucket avg 8192, max ~8600)

typedef __bf16 bf16x8 __attribute__((ext_vector_type(8)));
typedef float f32x4 __attribute__((ext_vector_type(4)));

__device__ __forceinline__ float bflo(uint v) { return __uint_as_float(v << 16); }
__device__ __forceinline__ float bfhi(uint v) { return __uint_as_float(v & 0xffff0000u); }

// ---------------- P1a: per-block bucket histograms (dst and src) + prepW/pad tail blocks ----------------
__global__ __launch_bounds__(256) void k_p1a(const int* __restrict__ src,
                                             const int* __restrict__ dst,
                                             int* __restrict__ ghd,
                                             int* __restrict__ ghs,
                                             const float* __restrict__ W,
                                             __bf16* __restrict__ Wt) {
  if (blockIdx.x >= P1B) {
    int i = (blockIdx.x - P1B) * 256 + threadIdx.x;
    if (i < SCLP - SCL) { ghd[SCL + i] = 0; ghs[SCL + i] = 0; }
    int n = i & 127, k = i >> 7;
    Wt[n * INF + k] = (__bf16)W[k * OUTF + n];
    return;
  }
  __shared__ int lhd[NBKT], lhs[NBKT];
  const int t = threadIdx.x;
  if (t < NBKT) { lhd[t] = 0; lhs[t] = 0; }
  __syncthreads();
  const int base = blockIdx.x * EPB;
#pragma unroll
  for (int i = 0; i < EPB / 256; ++i) {
    int e = base + i * 256 + t;
    atomicAdd(&lhd[dst[e] >> BSH], 1);
    atomicAdd(&lhs[src[e] >> BSH], 1);
  }
  __syncthreads();
  if (t < NBKT) {
    ghd[t * P1B + blockIdx.x] = lhd[t];
    ghs[t * P1B + blockIdx.x] = lhs[t];
  }
}

// ---------------- P1b: exclusive scan, vectorized (int4 x12 per thread, shuffle scan) ----------------
__global__ __launch_bounds__(1024) void k_p1b(int* __restrict__ ghd,
                                              int* __restrict__ ghs,
                                              int* __restrict__ row_start) {
  int* a = blockIdx.x ? ghs : ghd;
  __shared__ int wsum[16];
  const int t = threadIdx.x;
  const int lane = t & 63, wid = t >> 6;
  int4 v[12];
  const int4* p = (const int4*)(a + t * 48);
#pragma unroll
  for (int i = 0; i < 12; ++i) v[i] = p[i];
  int s = 0;
#pragma unroll
  for (int i = 0; i < 12; ++i) s += v[i].x + v[i].y + v[i].z + v[i].w;
  const int mysum = s;
#pragma unroll
  for (int d = 1; d < 64; d <<= 1) {
    int u = __shfl_up(s, d);
    if (lane >= d) s += u;
  }
  if (lane == 63) wsum[wid] = s;
  __syncthreads();
  if (wid == 0) {
    int ws = (lane < 16) ? wsum[lane] : 0;
    int inc = ws;
#pragma unroll
    for (int d = 1; d < 16; d <<= 1) {
      int u = __shfl_up(inc, d);
      if (lane >= d) inc += u;
    }
    if (lane < 16) wsum[lane] = inc - ws;  // exclusive wave offset
  }
  __syncthreads();
  int ex = wsum[wid] + s - mysum;
#pragma unroll
  for (int i = 0; i < 12; ++i) {
    int4 w;
    w.x = ex; ex += v[i].x;
    w.y = ex; ex += v[i].y;
    w.z = ex; ex += v[i].z;
    w.w = ex; ex += v[i].w;
    ((int4*)(a + t * 48))[i] = w;
  }
  if (blockIdx.x == 0 && t == 0) row_start[NN] = NE;
}

// ---------------- P1c: LDS staging-sort then coalesced flush (rec_d, rec_s) ----------------
__global__ __launch_bounds__(256) void k_p1c(const int* __restrict__ src,
                                             const int* __restrict__ dst,
                                             const int* __restrict__ ghd,
                                             const int* __restrict__ ghs,
                                             uint* __restrict__ rec_d,
                                             ushort* __restrict__ rec_s) {
  __shared__ int hist[256];                 // 196 used (padded zeros for scan)
  __shared__ int off[NBKT];
  __shared__ int adj[NBKT];
  __shared__ int sc[256];
  __shared__ uint d4[EPB];                  // 25.6 KB (phase S reuses as ushort)
  __shared__ unsigned char bkt[EPB];        // 6.4 KB
  const int t = threadIdx.x;
  const int base = blockIdx.x * EPB;

  // ========== Phase D: dst buckets -> rec_d ==========
  hist[t] = 0;
  __syncthreads();
#pragma unroll
  for (int i = 0; i < EPB / 256; ++i)
    atomicAdd(&hist[dst[base + i * 256 + t] >> BSH], 1);
  __syncthreads();
  int hv = hist[t];
  sc[t] = hv;
  __syncthreads();
  for (int o = 1; o < 256; o <<= 1) {
    int add = (t >= o) ? sc[t - o] : 0;
    __syncthreads();
    sc[t] += add;
    __syncthreads();
  }
  int lstart = sc[t] - hv;  // exclusive local offset
  if (t < NBKT) {
    off[t] = lstart;
    adj[t] = ghd[t * P1B + blockIdx.x] - lstart;
  }
  __syncthreads();
#pragma unroll
  for (int i = 0; i < EPB / 256; ++i) {
    int e = base + i * 256 + t;
    int s = src[e], d = dst[e];
    int b = d >> BSH;
    int p = atomicAdd(&off[b], 1);
    d4[p] = ((uint)s << BSH) | (uint)(d & 511);
    bkt[p] = (unsigned char)b;
  }
  __syncthreads();
#pragma unroll
  for (int i = 0; i < EPB / 256; ++i) {
    int idx = i * 256 + t;
    rec_d[adj[bkt[idx]] + idx] = d4[idx];   // consecutive threads -> consecutive addrs
  }
  __syncthreads();

  // ========== Phase S: src buckets -> rec_s ==========
  hist[t] = 0;
  __syncthreads();
#pragma unroll
  for (int i = 0; i < EPB / 256; ++i)
    atomicAdd(&hist[src[base + i * 256 + t] >> BSH], 1);
  __syncthreads();
  hv = hist[t];
  sc[t] = hv;
  __syncthreads();
  for (int o = 1; o < 256; o <<= 1) {
    int add = (t >= o) ? sc[t - o] : 0;
    __syncthreads();
    sc[t] += add;
    __syncthreads();
  }
  lstart = sc[t] - hv;
  if (t < NBKT) {
    off[t] = lstart;
    adj[t] = ghs[t * P1B + blockIdx.x] - lstart;
  }
  __syncthreads();
  ushort* s2 = (ushort*)d4;
#pragma unroll
  for (int i = 0; i < EPB / 256; ++i) {
    int s = src[base + i * 256 + t];
    int b = s >> BSH;
    int p = atomicAdd(&off[b], 1);
    s2[p] = (ushort)(s & 511);
    bkt[p] = (unsigned char)b;
  }
  __syncthreads();
#pragma unroll
  for (int i = 0; i < EPB / 256; ++i) {
    int idx = i * 256 + t;
    rec_s[adj[bkt[idx]] + idx] = s2[idx];
  }
}

// ---------------- P2: per-bucket CSR build (LDS sort + coalesced flush) + ns ----------------
__global__ __launch_bounds__(256) void k_p2(const int* __restrict__ ghd,
                                            const int* __restrict__ ghs,
                                            const uint* __restrict__ rec_d,
                                            const ushort* __restrict__ rec_s,
                                            int* __restrict__ edge_src,
                                            int* __restrict__ row_start,
                                            float* __restrict__ ns) {
  __shared__ int lh[512];
  __shared__ int sc[256];
  __shared__ int lbuf[P2CAP];   // 40 KB
  const int k = blockIdx.x, t = threadIdx.x;
  {
    const int base = ghd[k * P1B];
    const int end = (k == NBKT - 1) ? NE : ghd[(k + 1) * P1B];
    const int cnt = end - base;
    lh[t] = 0; lh[t + 256] = 0;
    __syncthreads();
    for (int j = base + t; j < end; j += 256) atomicAdd(&lh[rec_d[j] & 511], 1);
    __syncthreads();
    int a0 = lh[2 * t], a1 = lh[2 * t + 1];
    sc[t] = a0 + a1;
    __syncthreads();
    for (int off = 1; off < 256; off <<= 1) {
      int add = (t >= off) ? sc[t - off] : 0;
      __syncthreads();
      sc[t] += add;
      __syncthreads();
    }
    int ex = t ? sc[t - 1] : 0;
    int e0 = ex, e1 = ex + a0;            // RELATIVE positions within bucket
    int n0 = k * 512 + 2 * t;
    if (n0 < NN) row_start[n0] = base + e0;
    if (n0 + 1 < NN) row_start[n0 + 1] = base + e1;
    __syncthreads();
    lh[2 * t] = e0;
    lh[2 * t + 1] = e1;
    __syncthreads();
    if (cnt <= P2CAP) {
      for (int j = base + t; j < end; j += 256) {
        uint r = rec_d[j];
        int p = atomicAdd(&lh[r & 511], 1);
        lbuf[p] = (int)(r >> BSH);
      }
      __syncthreads();
      for (int i = t; i < cnt; i += 256)
        edge_src[base + i] = lbuf[i];      // perfectly coalesced
    } else {
      for (int j = base + t; j < end; j += 256) {
        uint r = rec_d[j];
        int p = atomicAdd(&lh[r & 511], 1);
        edge_src[base + p] = (int)(r >> BSH);
      }
    }
  }
  __syncthreads();
  {
    const int base = ghs[k * P1B];
    const int end = (k == NBKT - 1) ? NE : ghs[(k + 1) * P1B];
    lh[t] = 0; lh[t + 256] = 0;
    __syncthreads();
    for (int j = base + t; j < end; j += 256) atomicAdd(&lh[rec_s[j]], 1);
    __syncthreads();
    int n0 = k * 512 + t, n1 = n0 + 256;
    if (n0 < NN) { int c = lh[t];       ns[n0] = rsqrtf((float)(c > 1 ? c : 1)); }
    if (n1 < NN) { int c = lh[t + 256]; ns[n1] = rsqrtf((float)(c > 1 ? c : 1)); }
  }
}

// ---------------- MFMA GEMM: h = row-major(ns ⊙ (feat @ W)), bf16 out ----------------
// B in LDS once (lgkmcnt), A direct global->reg with depth-4 ring prefetch (vmcnt),
// no in-loop barriers.
__global__ __launch_bounds__(512, 4) void k_gemm(const float* __restrict__ feat,
                                                 const __bf16* __restrict__ Wt,
                                                 const float* __restrict__ ns,
                                                 __bf16* __restrict__ h) {
  __shared__ __attribute__((aligned(16))) char lB[65536];  // [col][256k] bf16, swizzled
  const int tid = threadIdx.x;
  const int w = tid >> 6, l = tid & 63;
  const int lr = l & 15, kg = l >> 4;
  const int row0 = blockIdx.x * 128 + w * 16;

#pragma unroll
  for (int i = 0; i < 8; ++i) {
    int c = i * 512 + tid;
    int col = c >> 5, g = c & 31;
    bf16x8 v = *(const bf16x8*)(Wt + (size_t)col * INF + g * 8);
    *(bf16x8*)(lB + col * 512 + ((g ^ (col & 7)) * 16)) = v;
  }
  __syncthreads();

  int r0 = row0 + lr; if (r0 >= NN) r0 = NN - 1;
  const float4* ap4k = (const float4*)(feat + (size_t)r0 * INF) + kg * 2;

  f32x4 acc[8];
#pragma unroll
  for (int j = 0; j < 8; ++j) acc[j] = (f32x4)0.0f;

  const char* bb = lB + lr * 512;
  const int lx = lr & 7;

  float4 buf0[4], buf1[4];
#pragma unroll
  for (int i = 0; i < 4; ++i) {
    buf0[i] = ap4k[i * 8];
    buf1[i] = ap4k[i * 8 + 1];
  }
#pragma unroll
  for (int kk = 0; kk < 8; ++kk) {
    float4 c0 = buf0[kk & 3], c1 = buf1[kk & 3];
    if (kk < 4) {
      buf0[kk & 3] = ap4k[(kk + 4) * 8];
      buf1[kk & 3] = ap4k[(kk + 4) * 8 + 1];
    }
    bf16x8 a;
#pragma unroll
    for (int j = 0; j < 4; ++j) {
      a[j] = (__bf16)c0[j];
      a[4 + j] = (__bf16)c1[j];
    }
#pragma unroll
    for (int nf = 0; nf < 8; ++nf) {
      bf16x8 b = *(const bf16x8*)(bb + nf * 8192 + (((kk * 4 + kg) ^ lx) * 16));
      acc[nf] = __builtin_amdgcn_mfma_f32_16x16x32_bf16(a, b, acc[nf], 0, 0, 0);
    }
  }

#pragma unroll
  for (int r = 0; r < 4; ++r) {
    int row = row0 + kg * 4 + r;
    if (row < NN) {
      float nsv = ns[row];
      __bf16* hp = h + (size_t)row * OUTF + lr;
#pragma unroll
      for (int nf = 0; nf < 8; ++nf)
        hp[nf * 16] = (__bf16)(acc[nf][r] * nsv);
    }
  }
}

// ---------------- aggregation: out[n] = nd[n] * (sum h[src]) + b ----------------
__global__ __launch_bounds__(256) void k_aggr(const uint4* __restrict__ h4,
                                              const int* __restrict__ row_start,
                                              const int* __restrict__ edge_src,
                                              const float* __restrict__ bias,
                                              float* __restrict__ out) {
  const int wave = threadIdx.x >> 6;
  const int lane = threadIdx.x & 63;
  const int q = lane >> 4;    // quarter 0..3
  const int cl = lane & 15;   // 16B chunk within 256B row
  const int n = blockIdx.x * 4 + wave;  // grid = NN/4 exact
  const int s0 = row_start[n];
  const int s1 = row_start[n + 1];
  const int cnt = s1 - s0;

  float a0 = 0.f, a1 = 0.f, a2 = 0.f, a3 = 0.f, a4 = 0.f, a5 = 0.f, a6 = 0.f, a7 = 0.f;
  for (int j0 = 0; j0 < cnt; j0 += 64) {
    int nb = cnt - j0; if (nb > 64) nb = 64;
    int idv = 0;
    if (lane < nb) idv = edge_src[s0 + j0 + lane];
#pragma unroll 8
    for (int j = 0; j < nb; j += 4) {
      int jj = j + q;
      int e = __shfl(idv, jj);
      if (jj < nb) {
        uint4 v = h4[(size_t)e * 16 + cl];
        a0 += bflo(v.x); a1 += bfhi(v.x);
        a2 += bflo(v.y); a3 += bfhi(v.y);
        a4 += bflo(v.z); a5 += bfhi(v.z);
        a6 += bflo(v.w); a7 += bfhi(v.w);
      }
    }
  }
  a0 += __shfl_xor(a0, 16); a1 += __shfl_xor(a1, 16); a2 += __shfl_xor(a2, 16); a3 += __shfl_xor(a3, 16);
  a4 += __shfl_xor(a4, 16); a5 += __shfl_xor(a5, 16); a6 += __shfl_xor(a6, 16); a7 += __shfl_xor(a7, 16);
  a0 += __shfl_xor(a0, 32); a1 += __shfl_xor(a1, 32); a2 += __shfl_xor(a2, 32); a3 += __shfl_xor(a3, 32);
  a4 += __shfl_xor(a4, 32); a5 += __shfl_xor(a5, 32); a6 += __shfl_xor(a6, 32); a7 += __shfl_xor(a7, 32);

  if (q == 0) {
    float ndv = rsqrtf((float)(cnt > 1 ? cnt : 1));
    const float4* b4 = (const float4*)bias;
    float4 ba = b4[2 * cl], bb = b4[2 * cl + 1];
    float4 o0, o1;
    o0.x = a0 * ndv + ba.x; o0.y = a1 * ndv + ba.y; o0.z = a2 * ndv + ba.z; o0.w = a3 * ndv + ba.w;
    o1.x = a4 * ndv + bb.x; o1.y = a5 * ndv + bb.y; o1.z = a6 * ndv + bb.z; o1.w = a7 * ndv + bb.w;
    float4* op = (float4*)(out + (size_t)n * OUTF);
    op[2 * cl] = o0;
    op[2 * cl + 1] = o1;
  }
}

// ---------------- launch ----------------
extern "C" void kernel_launch(void* const* d_in, const int* in_sizes, int n_in,
                              void* d_out, int out_size, void* d_ws, size_t ws_size,
                              hipStream_t stream) {
  const float* feat = (const float*)d_in[0];
  const int* src = (const int*)d_in[1];
  const int* dst = (const int*)d_in[2];
  const float* Wm = (const float*)d_in[3];
  const float* bias = (const float*)d_in[4];
  float* out = (float*)d_out;

  char* ws = (char*)d_ws;
  __bf16* h        = (__bf16*)(ws + 0);            // 25,600,000 (row-major)
  __bf16* Wt       = (__bf16*)(ws + 25600000);     //     65,536
  int*    ghd      = (int*)(ws + 25665536);        //    196,608 (padded)
  int*    ghs      = (int*)(ws + 25862144);        //    196,608 (padded)
  uint*   rec_d    = (uint*)(ws + 26058752);       //  6,400,000
  ushort* rec_s    = (ushort*)(ws + 32458752);     //  3,200,000
  int*    edge_src = (int*)(ws + 35658752);        //  6,400,000
  int*    row_start= (int*)(ws + 42058752);        //    400,016
  float*  ns       = (float*)(ws + 42458768);      //    400,000

  k_p1a<<<P1B + 128, 256, 0, stream>>>(src, dst, ghd, ghs, Wm, Wt);
  k_p1b<<<2, 1024, 0, stream>>>(ghd, ghs, row_start);
  k_p1c<<<P1B, 256, 0, stream>>>(src, dst, ghd, ghs, rec_d, rec_s);
  k_p2<<<NBKT, 256, 0, stream>>>(ghd, ghs, rec_d, rec_s, edge_src, row_start, ns);
  k_gemm<<<(NN + 127) / 128, 512, 0, stream>>>(feat, Wt, ns, h);
  k_aggr<<<NN / 4, 256, 0, stream>>>((const uint4*)h, row_start, edge_src, bias, out);
}